// Round 13
// baseline (626.130 us; speedup 1.0000x reference)
//
#include <hip/hip_runtime.h>
#include <cstdint>
#include <cstddef>

// Problem constants
#define N_ROWS  16384      // 4*4096 tokens
#define D_MOD   1024
#define D_LAT   4096
#define K_TOP   16

typedef _Float16 f16_t;
typedef _Float16 half8 __attribute__((ext_vector_type(8)));
typedef _Float16 half4 __attribute__((ext_vector_type(4)));
typedef float f32x4 __attribute__((ext_vector_type(4)));

// ws layout element offsets (f16) — must match kernel_launch
#define XL_OFF  16777216u   // (50331648-16777216)/2
#define WL_OFF  4194304u    // (92274688-83886080)/2

// ---------------------------------------------------------------------------
// global_load_lds helper (16B per lane, LDS dest = wave-uniform base + lane*16)
// ---------------------------------------------------------------------------
__device__ __forceinline__ void gload_lds16(const void* g, void* l) {
    __builtin_amdgcn_global_load_lds(
        (const __attribute__((address_space(1))) void*)g,
        (__attribute__((address_space(3))) void*)l, 16, 0, 0);
}

// ---------------------------------------------------------------------------
// Kernel: split fp32 -> fp16 hi + fp16 lo*2^11  (exact Fast2Sum residual)
// ---------------------------------------------------------------------------
__global__ __launch_bounds__(256) void split_f16(
    const float* __restrict__ src, f16_t* __restrict__ hi,
    f16_t* __restrict__ lo, int n4)
{
    const int i = blockIdx.x * 256 + threadIdx.x;
    if (i >= n4) return;
    const float4 v = ((const float4*)src)[i];
    union { f16_t h[4]; ushort4 u; } ph, pl;
    ph.h[0] = (f16_t)v.x; ph.h[1] = (f16_t)v.y;
    ph.h[2] = (f16_t)v.z; ph.h[3] = (f16_t)v.w;
    pl.h[0] = (f16_t)((v.x - (float)ph.h[0]) * 2048.0f);
    pl.h[1] = (f16_t)((v.y - (float)ph.h[1]) * 2048.0f);
    pl.h[2] = (f16_t)((v.z - (float)ph.h[2]) * 2048.0f);
    pl.h[3] = (f16_t)((v.w - (float)ph.h[3]) * 2048.0f);
    ((ushort4*)hi)[i] = ph.u;
    ((ushort4*)lo)[i] = pl.u;
}

// ---------------------------------------------------------------------------
// Kernel: transpose dec_w [1024][4096] -> decT f16 [4096][1024]
// ---------------------------------------------------------------------------
__global__ __launch_bounds__(256) void transpose_dec(
    const float* __restrict__ DW, f16_t* __restrict__ DT)
{
    __shared__ float tile[32][33];
    const int l0 = blockIdx.x * 32;
    const int d0 = blockIdx.y * 32;
    const int tx = threadIdx.x & 31;
    const int ty = threadIdx.x >> 5;
    #pragma unroll
    for (int i = 0; i < 32; i += 8)
        tile[ty + i][tx] = DW[(size_t)(d0 + ty + i) * D_LAT + l0 + tx];
    __syncthreads();
    #pragma unroll
    for (int i = 0; i < 32; i += 8)
        DT[(size_t)(l0 + ty + i) * D_MOD + d0 + tx] = (f16_t)tile[tx][ty + i];
}

// ---------------------------------------------------------------------------
// Fused MFMA GEMM, 8-phase-style schedule (m201 template adapted):
// tile 256(M)x128(N), BK=32, 8 waves of 64x64, TRIPLE-buffered LDS (3x48KB).
// pre = xh*wh + (xh*wl + xl*wh)/2048 + bias.
// Per K-step: 4 quadrant-phases, each {1-2 gloads(tile t+2) || 4-8 ds_reads
// -> setprio(1) -> 12 MFMA -> setprio(0) -> s_barrier -> sched_barrier(0)}.
// Prefetch depth 2 via 3 buffers -> iter-end wait is vmcnt(6): tile t+1's
// loads are waited, tile t+2's STAY IN FLIGHT (T4; impossible with 2 bufs).
// sched_barrier(0) at phase boundaries stops the compiler re-merging all
// ds_reads to the loop top (the r6-r12 serial-sum failure mode).
// Race ledger: reads(t) <- prior iter vmcnt(6)+barrier (t's 6 loads oldest
// of <=12 outstanding); gloads(t+2) -> buf[(t+2)%3]=buf read at t-1, sealed
// by t-1's end barrier. Swizzle formulas = r10 (measured 0 bank conflicts):
// stage gc=(l&3)^((l>>3)&3), read rc=(l>>4)^((l>>1)&3), linear LDS dest.
// ---------------------------------------------------------------------------
__global__ __launch_bounds__(512, 2) void enc_gemm_f16(
    const f16_t* __restrict__ XH, const f16_t* __restrict__ WH,
    const float* __restrict__ B1, const float* __restrict__ B2,
    float* __restrict__ PRE)
{
    extern __shared__ char smem[];   // 3 bufs x {AH 16K|AL 16K|BH 8K|BL 8K}

    const int tid = threadIdx.x;
    const int w = tid >> 6;          // 0..7
    const int l = tid & 63;

    // XCD-bijective swizzle (2048 blocks % 8 == 0)
    const int bid = blockIdx.x;
    const int swz = (bid & 7) * 256 + (bid >> 3);
    const int bx = swz & 31;          // 32 n-blocks (128 cols)
    const int by = swz >> 5;          // 64 m-blocks (256 rows)
    const int m0 = by * 256, n0 = bx * 128;
    const int wm = w >> 1;            // 0..3 (64-row band)
    const int wn = w & 1;             // 0..1 (64-col band)

    f32x4 acc1[4][4], acc2[4][4];
    #pragma unroll
    for (int i = 0; i < 4; ++i)
        #pragma unroll
        for (int j = 0; j < 4; ++j) {
            acc1[i][j] = (f32x4)(0.0f);
            acc2[i][j] = (f32x4)(0.0f);
        }

    const int q  = l >> 2;                    // row within 16-row slab
    const int gc = (l & 3) ^ ((l >> 3) & 3);  // pre-swizzled source k-chunk
    const int rc = (l >> 4) ^ ((l >> 1) & 3); // MFMA-read swizzled chunk
    const int fr = l & 15;

    const size_t abase = (size_t)m0 * D_MOD;
    const size_t bbase = (size_t)n0 * D_MOD;
    const f16_t* XL = XH + XL_OFF;
    const f16_t* WL = WH + WL_OFF;

#define LD8(P) (*(const half8*)(P))
#define CELL(MI, NI)                                                          \
    acc1[MI][NI] = __builtin_amdgcn_mfma_f32_16x16x32_f16(                    \
        ah[MI], bh[NI], acc1[MI][NI], 0, 0, 0);                               \
    acc2[MI][NI] = __builtin_amdgcn_mfma_f32_16x16x32_f16(                    \
        ah[MI], bl[NI], acc2[MI][NI], 0, 0, 0);                               \
    acc2[MI][NI] = __builtin_amdgcn_mfma_f32_16x16x32_f16(                    \
        al[MI], bh[NI], acc2[MI][NI], 0, 0, 0);

    // full-tile stage: 6 gloads/lane (A slabs w, w+8; B slab w)
#define STAGE_ALL(BB, K0)                                                     \
    {                                                                         \
        char* sb = (BB);                                                      \
        const size_t goA0 = (size_t)(w * 16 + q) * D_MOD + (K0) + gc * 8;     \
        const size_t goA1 = (size_t)((w + 8) * 16 + q) * D_MOD + (K0) + gc * 8; \
        const size_t goB  = (size_t)(w * 16 + q) * D_MOD + (K0) + gc * 8;     \
        gload_lds16(XH + abase + goA0, sb + w * 1024);                        \
        gload_lds16(XL + abase + goA0, sb + 16384 + w * 1024);                \
        gload_lds16(XH + abase + goA1, sb + (w + 8) * 1024);                  \
        gload_lds16(XL + abase + goA1, sb + 16384 + (w + 8) * 1024);          \
        gload_lds16(WH + bbase + goB, sb + 32768 + w * 1024);                 \
        gload_lds16(WL + bbase + goB, sb + 40960 + w * 1024);                 \
    }

    STAGE_ALL(smem, 0);               // tile 0 -> buf0
    STAGE_ALL(smem + 49152, 32);      // tile 1 -> buf1  (12 in flight)
    asm volatile("s_waitcnt vmcnt(6)" ::: "memory");   // tile0 landed
    __builtin_amdgcn_s_barrier();
    __builtin_amdgcn_sched_barrier(0);

    int cur = 0;
    for (int t = 0; t < 32; ++t) {
        char* cb = smem + cur * 49152;
        char* nb = smem + ((cur >= 1) ? (cur - 1) : 2) * 49152;  // (cur+2)%3
        const int k2 = (t + 2) * 32;
        const int pf = (t <= 29);

        const char* AsH = cb;
        const char* AsL = cb + 16384;
        const char* BsH = cb + 32768;
        const char* BsL = cb + 40960;

        half8 ah[4], al[4], bh[4], bl[4];

        // ---- phase Q00: prefetch A-slab0, read a01/b01, cells mi01 x ni01 --
        if (pf) {
            const size_t go = (size_t)(w * 16 + q) * D_MOD + k2 + gc * 8;
            gload_lds16(XH + abase + go, nb + w * 1024);
            gload_lds16(XL + abase + go, nb + 16384 + w * 1024);
        }
        {
            const int r0 = (wm * 64 + fr) * 64, r1 = (wm * 64 + 16 + fr) * 64;
            const int c0 = (wn * 64 + fr) * 64, c1 = (wn * 64 + 16 + fr) * 64;
            ah[0] = LD8(AsH + r0 + rc * 16); al[0] = LD8(AsL + r0 + rc * 16);
            ah[1] = LD8(AsH + r1 + rc * 16); al[1] = LD8(AsL + r1 + rc * 16);
            bh[0] = LD8(BsH + c0 + rc * 16); bl[0] = LD8(BsL + c0 + rc * 16);
            bh[1] = LD8(BsH + c1 + rc * 16); bl[1] = LD8(BsL + c1 + rc * 16);
        }
        __builtin_amdgcn_s_setprio(1);
        CELL(0, 0) CELL(0, 1) CELL(1, 0) CELL(1, 1)
        __builtin_amdgcn_s_setprio(0);
        __builtin_amdgcn_s_barrier();
        __builtin_amdgcn_sched_barrier(0);

        // ---- phase Q01: prefetch A-slab1, read b23, cells mi01 x ni23 ------
        if (pf) {
            const size_t go = (size_t)((w + 8) * 16 + q) * D_MOD + k2 + gc * 8;
            gload_lds16(XH + abase + go, nb + (w + 8) * 1024);
            gload_lds16(XL + abase + go, nb + 16384 + (w + 8) * 1024);
        }
        {
            const int c2 = (wn * 64 + 32 + fr) * 64, c3 = (wn * 64 + 48 + fr) * 64;
            bh[2] = LD8(BsH + c2 + rc * 16); bl[2] = LD8(BsL + c2 + rc * 16);
            bh[3] = LD8(BsH + c3 + rc * 16); bl[3] = LD8(BsL + c3 + rc * 16);
        }
        __builtin_amdgcn_s_setprio(1);
        CELL(0, 2) CELL(0, 3) CELL(1, 2) CELL(1, 3)
        __builtin_amdgcn_s_setprio(0);
        __builtin_amdgcn_s_barrier();
        __builtin_amdgcn_sched_barrier(0);

        // ---- phase Q10: prefetch B, read a23, cells mi23 x ni01 ------------
        if (pf) {
            const size_t go = (size_t)(w * 16 + q) * D_MOD + k2 + gc * 8;
            gload_lds16(WH + bbase + go, nb + 32768 + w * 1024);
            gload_lds16(WL + bbase + go, nb + 40960 + w * 1024);
        }
        {
            const int r2 = (wm * 64 + 32 + fr) * 64, r3 = (wm * 64 + 48 + fr) * 64;
            ah[2] = LD8(AsH + r2 + rc * 16); al[2] = LD8(AsL + r2 + rc * 16);
            ah[3] = LD8(AsH + r3 + rc * 16); al[3] = LD8(AsL + r3 + rc * 16);
        }
        __builtin_amdgcn_s_setprio(1);
        CELL(2, 0) CELL(2, 1) CELL(3, 0) CELL(3, 1)
        __builtin_amdgcn_s_setprio(0);
        __builtin_amdgcn_s_barrier();
        __builtin_amdgcn_sched_barrier(0);

        // ---- phase Q11: cells mi23 x ni23; iter-end counted wait -----------
        __builtin_amdgcn_s_setprio(1);
        CELL(2, 2) CELL(2, 3) CELL(3, 2) CELL(3, 3)
        __builtin_amdgcn_s_setprio(0);
        if (t <= 29) {
            // wait tile t+1's 6 loads (oldest); tile t+2's 6 stay in flight
            asm volatile("s_waitcnt vmcnt(6)" ::: "memory");
        } else if (t == 30) {
            asm volatile("s_waitcnt vmcnt(0)" ::: "memory");
        }
        __builtin_amdgcn_s_barrier();
        __builtin_amdgcn_sched_barrier(0);

        cur = (cur == 2) ? 0 : cur + 1;
    }
#undef STAGE_ALL
#undef CELL
#undef LD8

    // epilogue: pre = acc1 + acc2/2048 + bias
    const int lrow = (l >> 4) * 4;
    const int lcol = l & 15;
    #pragma unroll
    for (int ni = 0; ni < 4; ++ni) {
        const int col = n0 + wn * 64 + ni * 16 + lcol;
        const float bias = B1[col] + B2[col];
        #pragma unroll
        for (int mi = 0; mi < 4; ++mi) {
            const int row = m0 + wm * 64 + mi * 16 + lrow;
            #pragma unroll
            for (int j = 0; j < 4; ++j)
                PRE[(size_t)(row + j) * D_LAT + col] =
                    acc1[mi][ni][j] + acc2[mi][ni][j] * (1.0f / 2048.0f) + bias;
        }
    }
}

// ---------------------------------------------------------------------------
// Fallback: fp32 VALU GEMM (round-1, known-good)
// ---------------------------------------------------------------------------
__global__ __launch_bounds__(256) void enc_gemm_f32(
    const float* __restrict__ X, const float* __restrict__ W,
    const float* __restrict__ B1, const float* __restrict__ B2,
    float* __restrict__ PRE)
{
    __shared__ float Asm[16][128];
    __shared__ float Bsm[16][128];
    const int tid = threadIdx.x;
    const int m0 = blockIdx.y * 128;
    const int n0 = blockIdx.x * 128;
    const int tx = tid & 15;
    const int ty = tid >> 4;
    const int lr = tid >> 2;
    const int lk = (tid & 3) << 2;

    float acc[8][8];
    #pragma unroll
    for (int i = 0; i < 8; ++i)
        #pragma unroll
        for (int j = 0; j < 8; ++j) acc[i][j] = 0.f;

    const float* xp0 = X + (size_t)(m0 + lr) * D_MOD + lk;
    const float* xp1 = X + (size_t)(m0 + lr + 64) * D_MOD + lk;
    const float* wp0 = W + (size_t)(n0 + lr) * D_MOD + lk;
    const float* wp1 = W + (size_t)(n0 + lr + 64) * D_MOD + lk;

    for (int k0 = 0; k0 < D_MOD; k0 += 16) {
        const float4 a0 = *(const float4*)(xp0 + k0);
        const float4 a1 = *(const float4*)(xp1 + k0);
        const float4 b0 = *(const float4*)(wp0 + k0);
        const float4 b1 = *(const float4*)(wp1 + k0);
        __syncthreads();
        Asm[lk + 0][lr]      = a0.x; Asm[lk + 1][lr]      = a0.y;
        Asm[lk + 2][lr]      = a0.z; Asm[lk + 3][lr]      = a0.w;
        Asm[lk + 0][lr + 64] = a1.x; Asm[lk + 1][lr + 64] = a1.y;
        Asm[lk + 2][lr + 64] = a1.z; Asm[lk + 3][lr + 64] = a1.w;
        Bsm[lk + 0][lr]      = b0.x; Bsm[lk + 1][lr]      = b0.y;
        Bsm[lk + 2][lr]      = b0.z; Bsm[lk + 3][lr]      = b0.w;
        Bsm[lk + 0][lr + 64] = b1.x; Bsm[lk + 1][lr + 64] = b1.y;
        Bsm[lk + 2][lr + 64] = b1.z; Bsm[lk + 3][lr + 64] = b1.w;
        __syncthreads();
        #pragma unroll
        for (int kk = 0; kk < 16; ++kk) {
            float a[8], b[8];
            *(float4*)&a[0] = *(const float4*)&Asm[kk][ty * 8];
            *(float4*)&a[4] = *(const float4*)&Asm[kk][ty * 8 + 4];
            *(float4*)&b[0] = *(const float4*)&Bsm[kk][tx * 8];
            *(float4*)&b[4] = *(const float4*)&Bsm[kk][tx * 8 + 4];
            #pragma unroll
            for (int i = 0; i < 8; ++i)
                #pragma unroll
                for (int j = 0; j < 8; ++j)
                    acc[i][j] = fmaf(a[i], b[j], acc[i][j]);
        }
    }

    float bias[8];
    #pragma unroll
    for (int j = 0; j < 8; ++j) {
        const int col = n0 + tx * 8 + j;
        bias[j] = B1[col] + B2[col];
    }
    #pragma unroll
    for (int i = 0; i < 8; ++i) {
        const size_t off = (size_t)(m0 + ty * 8 + i) * D_LAT + n0 + tx * 8;
        float4 o0, o1;
        o0.x = acc[i][0] + bias[0]; o0.y = acc[i][1] + bias[1];
        o0.z = acc[i][2] + bias[2]; o0.w = acc[i][3] + bias[3];
        o1.x = acc[i][4] + bias[4]; o1.y = acc[i][5] + bias[5];
        o1.z = acc[i][6] + bias[6]; o1.w = acc[i][7] + bias[7];
        *(float4*)&PRE[off]     = o0;
        *(float4*)&PRE[off + 4] = o1;
    }
}

// ---------------------------------------------------------------------------
// Kernel: per-row top-16 via 2-round radix-select + short exact extraction.
// float4 I/O; decode gathers DT in f16 (round-12, measured good)
// ---------------------------------------------------------------------------
__global__ __launch_bounds__(256) void topk_decode(
    float* __restrict__ LAT, const f16_t* __restrict__ DT,
    const float* __restrict__ DW, float* __restrict__ REC, const int use_t)
{
    const int row = blockIdx.x;
    const int t = threadIdx.x;
    const int wv = t >> 6;
    const int ln = t & 63;
    float* prow = LAT + (size_t)row * D_LAT;
    float4* pv4 = (float4*)prow;

    __shared__ uint32_t hist[4096];     // 16KB, transposed layout
    __shared__ uint32_t h2[256];        // refinement histogram
    __shared__ uint32_t wsum[4];
    __shared__ uint32_t sh_b1, sh_cgt1, sh_prefix, sh_cgt2;
    __shared__ uint32_t s_wk[4];
    __shared__ int      s_wi[4];
    __shared__ float    topv[K_TOP];
    __shared__ int      topi[K_TOP];
    __shared__ uint32_t sh_cnt;

    // load row: 4 x float4 per thread (16B/lane, coalesced)
    float v[16];
    #pragma unroll
    for (int j = 0; j < 4; ++j) {
        const float4 f = pv4[t + 256 * j];
        v[j * 4 + 0] = f.x; v[j * 4 + 1] = f.y;
        v[j * 4 + 2] = f.z; v[j * 4 + 3] = f.w;
    }

    // monotone key: larger key <=> larger float (finite data)
    uint32_t key[16];
    #pragma unroll
    for (int jj = 0; jj < 16; ++jj) {
        const uint32_t b = __float_as_uint(v[jj]);
        key[jj] = (b & 0x80000000u) ? ~b : (b | 0x80000000u);
    }

    // phase 0: zero histograms (uint4 stores)
    uint4* h4 = (uint4*)hist;
    #pragma unroll
    for (int i = 0; i < 4; ++i) h4[t + 256 * i] = make_uint4(0u, 0u, 0u, 0u);
    h2[t] = 0;
    if (t == 0) sh_cnt = 0;
    __syncthreads();

    // phase 1: 12-bit histogram (transposed addressing)
    #pragma unroll
    for (int jj = 0; jj < 16; ++jj) {
        const uint32_t bin = key[jj] >> 20;
        atomicAdd(&hist[(bin & 15u) * 256 + (bin >> 4)], 1u);
    }
    __syncthreads();

    // phase 2: block suffix-scan over 256 chunks of 16 bins; find rank-16 bin
    uint32_t s = 0;
    #pragma unroll
    for (int b = 0; b < 16; ++b) s += hist[b * 256 + t];
    uint32_t suf = s;                       // inclusive suffix within wave
    #pragma unroll
    for (int off = 1; off <= 32; off <<= 1) {
        const uint32_t o = __shfl_down(suf, off);
        if (ln + off < 64) suf += o;
    }
    if (ln == 0) wsum[wv] = suf;
    __syncthreads();
    uint32_t above = suf - s;               // lanes > ln, same wave
    for (int w2 = wv + 1; w2 < 4; ++w2) above += wsum[w2];
    if (above < K_TOP && above + s >= K_TOP) {   // unique owner chunk
        uint32_t acc = above;
        for (int b = 15; b >= 0; --b) {
            const uint32_t h = hist[b * 256 + t];
            if (acc + h >= K_TOP) { sh_b1 = (uint32_t)(t * 16 + b); sh_cgt1 = acc; break; }
            acc += h;
        }
    }
    __syncthreads();
    const uint32_t b1 = sh_b1;
    const uint32_t cgt1 = sh_cgt1;
    const uint32_t need1 = K_TOP - cgt1;

    // phase 3: refine on bits [19:12] among prefix-matched values
    #pragma unroll
    for (int jj = 0; jj < 16; ++jj)
        if ((key[jj] >> 20) == b1) atomicAdd(&h2[(key[jj] >> 12) & 255u], 1u);
    __syncthreads();

    // phase 4: wave 0 suffix-scans h2 (4 bins/lane)
    if (wv == 0) {
        const int base = ln * 4;
        const uint32_t s2 = h2[base] + h2[base + 1] + h2[base + 2] + h2[base + 3];
        uint32_t suf2 = s2;
        #pragma unroll
        for (int off = 1; off <= 32; off <<= 1) {
            const uint32_t o = __shfl_down(suf2, off);
            if (ln + off < 64) suf2 += o;
        }
        const uint32_t E = suf2 - s2;       // bins in lanes > ln
        if (E < need1 && E + s2 >= need1) {
            uint32_t acc = E;
            for (int b = 3; b >= 0; --b) {
                const uint32_t h = h2[base + b];
                if (acc + h >= need1) {
                    sh_prefix = (b1 << 8) | (uint32_t)(base + b);
                    sh_cgt2 = cgt1 + acc;
                    break;
                }
                acc += h;
            }
        }
    }
    __syncthreads();
    const uint32_t prefix = sh_prefix;
    const uint32_t need_in = K_TOP - sh_cgt2;   // >= 1, uniform

    // phase 5: selection by 20-bit prefix; exact extraction for the boundary
    // element index for slot jj: l = ((jj>>2)<<10) | (t<<2) | (jj&3)
    uint32_t sel = 0, candm = 0;
    #pragma unroll
    for (int jj = 0; jj < 16; ++jj) {
        const uint32_t p = key[jj] >> 12;
        if (p > prefix) sel |= 1u << jj;
        else if (p == prefix) candm |= 1u << jj;
    }
    for (uint32_t e = 0; e < need_in; ++e) {
        uint32_t bk = 0; int bi = 0x7FFFFFFF;
        #pragma unroll
        for (int jj = 0; jj < 16; ++jj) {
            if ((candm >> jj) & 1u) {
                const int lj = ((jj >> 2) << 10) | (t << 2) | (jj & 3);
                if (key[jj] > bk || (key[jj] == bk && lj < bi)) { bk = key[jj]; bi = lj; }
            }
        }
        #pragma unroll
        for (int off = 32; off >= 1; off >>= 1) {
            const uint32_t ok = __shfl_xor(bk, off);
            const int      oi = __shfl_xor(bi, off);
            if (ok > bk || (ok == bk && oi < bi)) { bk = ok; bi = oi; }
        }
        if (ln == 0) { s_wk[wv] = bk; s_wi[wv] = bi; }
        __syncthreads();
        uint32_t fk = s_wk[0]; int fi = s_wi[0];
        for (int w2 = 1; w2 < 4; ++w2)
            if (s_wk[w2] > fk || (s_wk[w2] == fk && s_wi[w2] < fi)) { fk = s_wk[w2]; fi = s_wi[w2]; }
        if (((fi >> 2) & 255) == t) {
            const int jj = (((fi >> 10) & 3) << 2) | (fi & 3);
            candm &= ~(1u << jj);
            sel   |=  (1u << jj);
        }
        __syncthreads();
    }

    // phase 6: sparse latents write (relu on selected, zero elsewhere), float4
    #pragma unroll
    for (int j = 0; j < 4; ++j) {
        float4 o;
        o.x = ((sel >> (j * 4 + 0)) & 1u) ? fmaxf(v[j * 4 + 0], 0.f) : 0.f;
        o.y = ((sel >> (j * 4 + 1)) & 1u) ? fmaxf(v[j * 4 + 1], 0.f) : 0.f;
        o.z = ((sel >> (j * 4 + 2)) & 1u) ? fmaxf(v[j * 4 + 2], 0.f) : 0.f;
        o.w = ((sel >> (j * 4 + 3)) & 1u) ? fmaxf(v[j * 4 + 3], 0.f) : 0.f;
        pv4[t + 256 * j] = o;
    }

    // phase 7: compact selected (val, idx) -> LDS (exactly 16)
    #pragma unroll
    for (int jj = 0; jj < 16; ++jj) {
        if ((sel >> jj) & 1u) {
            const uint32_t slot = atomicAdd(&sh_cnt, 1u);
            topv[slot] = v[jj];
            topi[slot] = ((jj >> 2) << 10) | (t << 2) | (jj & 3);
        }
    }
    __syncthreads();

    // phase 8: decode recon[row, d] = sum_k relu(val_k) * dec_w[d, l_k]
    float4 racc = make_float4(0.f, 0.f, 0.f, 0.f);
    if (use_t) {
        #pragma unroll
        for (int k = 0; k < K_TOP; ++k) {
            const float val = fmaxf(topv[k], 0.f);
            const half4 wr = *(const half4*)(DT + (size_t)topi[k] * D_MOD + 4 * t);
            racc.x = fmaf(val, (float)wr[0], racc.x);
            racc.y = fmaf(val, (float)wr[1], racc.y);
            racc.z = fmaf(val, (float)wr[2], racc.z);
            racc.w = fmaf(val, (float)wr[3], racc.w);
        }
    } else {
        #pragma unroll
        for (int k = 0; k < K_TOP; ++k) {
            const float val = fmaxf(topv[k], 0.f);
            const int   li  = topi[k];
            racc.x = fmaf(val, DW[(size_t)(4 * t + 0) * D_LAT + li], racc.x);
            racc.y = fmaf(val, DW[(size_t)(4 * t + 1) * D_LAT + li], racc.y);
            racc.z = fmaf(val, DW[(size_t)(4 * t + 2) * D_LAT + li], racc.z);
            racc.w = fmaf(val, DW[(size_t)(4 * t + 3) * D_LAT + li], racc.w);
        }
    }
    ((float4*)(REC + (size_t)row * D_MOD))[t] = racc;
}

// ---------------------------------------------------------------------------
extern "C" void kernel_launch(void* const* d_in, const int* in_sizes, int n_in,
                              void* d_out, int out_size, void* d_ws, size_t ws_size,
                              hipStream_t stream)
{
    const float* x      = (const float*)d_in[0];
    const float* enc_w  = (const float*)d_in[1];
    const float* enc_b  = (const float*)d_in[2];
    const float* enc_b2 = (const float*)d_in[3];
    const float* dec_w  = (const float*)d_in[4];

    float* recon   = (float*)d_out;                    // [16384,1024]
    float* latents = recon + (size_t)N_ROWS * D_MOD;   // [16384,4096]

    char* ws = (char*)d_ws;
    // ws layout (bytes): decT f16 [0,8.4M) | pad | xh | xl | wh | wl (f16)
    f16_t* decT = (f16_t*)ws;
    f16_t* xh = (f16_t*)(ws + 16777216);
    f16_t* xl = (f16_t*)(ws + 50331648);   // = xh + XL_OFF elems
    f16_t* wh = (f16_t*)(ws + 83886080);
    f16_t* wl = (f16_t*)(ws + 92274688);   // = wh + WL_OFF elems
    const size_t need_fast = 100663296;
    const size_t need_t    = 16777216;
    const int has_t = (ws_size >= need_t) ? 1 : 0;
    const int fast  = (ws_size >= need_fast) ? 1 : 0;

    if (has_t)
        transpose_dec<<<dim3(D_LAT / 32, D_MOD / 32), 256, 0, stream>>>(dec_w, decT);

    if (fast) {
        split_f16<<<(N_ROWS * D_MOD / 4) / 256, 256, 0, stream>>>(x, xh, xl, N_ROWS * D_MOD / 4);
        split_f16<<<(D_LAT * D_MOD / 4) / 256, 256, 0, stream>>>(enc_w, wh, wl, D_LAT * D_MOD / 4);
        // tile 256x128, 512 threads, 3x48KB = 144KB dynamic LDS
        enc_gemm_f16<<<(N_ROWS / 256) * (D_LAT / 128), 512, 147456, stream>>>(
            xh, wh, enc_b, enc_b2, latents);
    } else {
        enc_gemm_f32<<<dim3(D_LAT / 128, N_ROWS / 128), 256, 0, stream>>>(
            x, enc_w, enc_b, enc_b2, latents);
    }

    topk_decode<<<N_ROWS, 256, 0, stream>>>(latents, decT, dec_w, recon, has_t);
}

// Round 15
// 615.259 us; speedup vs baseline: 1.0177x; 1.0177x over previous
//
#include <hip/hip_runtime.h>
#include <cstdint>
#include <cstddef>

// Problem constants
#define N_ROWS  16384      // 4*4096 tokens
#define D_MOD   1024
#define D_LAT   4096
#define K_TOP   16

typedef _Float16 f16_t;
typedef _Float16 half8 __attribute__((ext_vector_type(8)));
typedef _Float16 half4 __attribute__((ext_vector_type(4)));
typedef float f32x4 __attribute__((ext_vector_type(4)));
typedef unsigned short u16x4 __attribute__((ext_vector_type(4)));
typedef unsigned int u32x4 __attribute__((ext_vector_type(4)));

// ws layout element offsets (f16) — must match kernel_launch
#define XL_OFF  16777216u   // (50331648-16777216)/2
#define WL_OFF  4194304u    // (92274688-83886080)/2

// prep-kernel grid segmentation
#define PREP_XBLK 16384     // x split: 16384*1024/4/256
#define PREP_WBLK 4096      // w split: 4096*1024/4/256
#define PREP_TBLK 4096      // transpose: 128*32

// ---------------------------------------------------------------------------
// global_load_lds helper (16B per lane, LDS dest = wave-uniform base + lane*16)
// ---------------------------------------------------------------------------
__device__ __forceinline__ void gload_lds16(const void* g, void* l) {
    __builtin_amdgcn_global_load_lds(
        (const __attribute__((address_space(1))) void*)g,
        (__attribute__((address_space(3))) void*)l, 16, 0, 0);
}

// ---------------------------------------------------------------------------
// Fused prep kernel: {split x, split enc_w, transpose dec_w} in ONE launch
// (all independent; branch on blockIdx). Split outputs stored nontemporal
// (streaming, read once by GEMM much later).
// ---------------------------------------------------------------------------
__global__ __launch_bounds__(256) void prep(
    const float* __restrict__ x, const float* __restrict__ enc_w,
    const float* __restrict__ dec_w,
    f16_t* __restrict__ xh, f16_t* __restrict__ xl,
    f16_t* __restrict__ wh, f16_t* __restrict__ wl,
    f16_t* __restrict__ DT)
{
    __shared__ float tile[32][33];
    const int bid = blockIdx.x;

    if (bid < PREP_XBLK + PREP_WBLK) {
        // ---- split fp32 -> f16 hi + f16 lo*2^11 (exact Fast2Sum residual) --
        const float* src; f16_t* hi; f16_t* lo; int i;
        if (bid < PREP_XBLK) {
            src = x;     hi = xh; lo = xl;
            i = bid * 256 + threadIdx.x;
        } else {
            src = enc_w; hi = wh; lo = wl;
            i = (bid - PREP_XBLK) * 256 + threadIdx.x;
        }
        const f32x4 v = ((const f32x4*)src)[i];
        union { f16_t h[4]; u16x4 u; } ph, pl;
        ph.h[0] = (f16_t)v[0]; ph.h[1] = (f16_t)v[1];
        ph.h[2] = (f16_t)v[2]; ph.h[3] = (f16_t)v[3];
        pl.h[0] = (f16_t)((v[0] - (float)ph.h[0]) * 2048.0f);
        pl.h[1] = (f16_t)((v[1] - (float)ph.h[1]) * 2048.0f);
        pl.h[2] = (f16_t)((v[2] - (float)ph.h[2]) * 2048.0f);
        pl.h[3] = (f16_t)((v[3] - (float)ph.h[3]) * 2048.0f);
        __builtin_nontemporal_store(ph.u, &((u16x4*)hi)[i]);
        __builtin_nontemporal_store(pl.u, &((u16x4*)lo)[i]);
    } else {
        // ---- transpose dec_w [1024][4096] -> decT f16 [4096][1024] ---------
        const int tb = bid - PREP_XBLK - PREP_WBLK;
        const int l0 = (tb & 127) * 32;   // along D_LAT
        const int d0 = (tb >> 7) * 32;    // along D_MOD
        const int tx = threadIdx.x & 31;
        const int ty = threadIdx.x >> 5;
        #pragma unroll
        for (int i = 0; i < 32; i += 8)
            tile[ty + i][tx] = dec_w[(size_t)(d0 + ty + i) * D_LAT + l0 + tx];
        __syncthreads();
        #pragma unroll
        for (int i = 0; i < 32; i += 8)
            DT[(size_t)(l0 + ty + i) * D_MOD + d0 + tx] = (f16_t)tile[tx][ty + i];
    }
}

// ---------------------------------------------------------------------------
// Fused MFMA GEMM, BK=64, 4 waves, wave tile 64x64 (round-12 version —
// measured best of 8 structure variants r6-r13: 424us, MfmaUtil 44%).
// pre = xh*wh + (xh*wl + xl*wh)/2048 + bias.
// A-subtile source pipeline; 64KB LDS 1-buffer 2-barrier loop;
// swizzle (chunk ^= row&7) via pre-swizzled global source, linear dest.
// NEW: pre stored NONTEMPORAL — the 268MB write stream was evicting
// the operand panels from L2/L3 (FETCH 814MB vs ~120MB compulsory).
// ---------------------------------------------------------------------------
__global__ __launch_bounds__(256, 2) void enc_gemm_f16(
    const f16_t* __restrict__ XH, const f16_t* __restrict__ WH,
    const float* __restrict__ B1, const float* __restrict__ B2,
    float* __restrict__ PRE)
{
    __shared__ char smem[65536];
    char* AsH = smem;
    char* AsL = smem + 16384;
    char* BsH = smem + 32768;
    char* BsL = smem + 49152;

    const int tid = threadIdx.x;
    const int w = tid >> 6;          // 0..3
    const int l = tid & 63;

    // XCD-bijective swizzle (4096 blocks % 8 == 0)
    const int bid = blockIdx.x;
    const int swz = (bid & 7) * 512 + (bid >> 3);
    const int bx = swz & 31;          // 32 n-blocks
    const int by = swz >> 5;          // 128 m-blocks
    const int m0 = by * 128, n0 = bx * 128;
    const int wm = w >> 1, wn = w & 1;

    f32x4 acc1[4][4], acc2[4][4];
    #pragma unroll
    for (int i = 0; i < 4; ++i)
        #pragma unroll
        for (int j = 0; j < 4; ++j) {
            acc1[i][j] = (f32x4)(0.0f);
            acc2[i][j] = (f32x4)(0.0f);
        }

    const int srow  = l >> 3;                 // 0..7 within 8-row chunk
    const int sclog = (l & 7) ^ srow;         // pre-swizzled logical chunk
    const size_t abase = (size_t)m0 * D_MOD;
    const size_t bbase = (size_t)n0 * D_MOD;
    const f16_t* XL = XH + XL_OFF;            // constant ws offsets
    const f16_t* WL = WH + WL_OFF;

    for (int k0 = 0; k0 < D_MOD; k0 += 64) {
        __syncthreads();   // all waves done reading LDS from previous step
        #pragma unroll
        for (int i = 0; i < 4; ++i) {
            const int cidx = i * 4 + w;                // 8-row chunk 0..15
            const size_t goff = (size_t)(cidx * 8 + srow) * D_MOD + k0 + sclog * 8;
            const int ldst = cidx * 1024;
            gload_lds16(XH + abase + goff, AsH + ldst);
            gload_lds16(XL + abase + goff, AsL + ldst);
            gload_lds16(WH + bbase + goff, BsH + ldst);
            gload_lds16(WL + bbase + goff, BsL + ldst);
        }
        __syncthreads();   // vmcnt(0) drained by compiler before barrier

        #pragma unroll
        for (int kk = 0; kk < 2; ++kk) {
            const int c = ((kk * 4) + (l >> 4)) ^ (l & 7);  // swizzled chunk
            half8 bh[4], bl[4];
            #pragma unroll
            for (int ni = 0; ni < 4; ++ni) {
                const int col = wn * 64 + ni * 16 + (l & 15);
                bh[ni] = *(const half8*)(BsH + col * 128 + c * 16);
                bl[ni] = *(const half8*)(BsL + col * 128 + c * 16);
            }
            const int rbase = wm * 64 + (l & 15);
            half8 ah = *(const half8*)(AsH + rbase * 128 + c * 16);
            half8 al = *(const half8*)(AsL + rbase * 128 + c * 16);
            #pragma unroll
            for (int mi = 0; mi < 4; ++mi) {
                half8 ah_n = ah, al_n = al;
                if (mi < 3) {   // issue NEXT subtile's reads before MFMAs
                    const int row = rbase + (mi + 1) * 16;
                    ah_n = *(const half8*)(AsH + row * 128 + c * 16);
                    al_n = *(const half8*)(AsL + row * 128 + c * 16);
                }
                #pragma unroll
                for (int ni = 0; ni < 4; ++ni)
                    acc1[mi][ni] = __builtin_amdgcn_mfma_f32_16x16x32_f16(
                        ah, bh[ni], acc1[mi][ni], 0, 0, 0);
                #pragma unroll
                for (int ni = 0; ni < 4; ++ni)
                    acc2[mi][ni] = __builtin_amdgcn_mfma_f32_16x16x32_f16(
                        ah, bl[ni], acc2[mi][ni], 0, 0, 0);
                #pragma unroll
                for (int ni = 0; ni < 4; ++ni)
                    acc2[mi][ni] = __builtin_amdgcn_mfma_f32_16x16x32_f16(
                        al, bh[ni], acc2[mi][ni], 0, 0, 0);
                ah = ah_n; al = al_n;
            }
        }
    }

    // epilogue: pre = acc1 + acc2/2048 + bias  (nontemporal stream)
    const int lrow = (l >> 4) * 4;
    const int lcol = l & 15;
    #pragma unroll
    for (int ni = 0; ni < 4; ++ni) {
        const int col = n0 + wn * 64 + ni * 16 + lcol;
        const float bias = B1[col] + B2[col];
        #pragma unroll
        for (int mi = 0; mi < 4; ++mi) {
            const int row = m0 + wm * 64 + mi * 16 + lrow;
            #pragma unroll
            for (int j = 0; j < 4; ++j) {
                const float val =
                    acc1[mi][ni][j] + acc2[mi][ni][j] * (1.0f / 2048.0f) + bias;
                __builtin_nontemporal_store(
                    val, &PRE[(size_t)(row + j) * D_LAT + col]);
            }
        }
    }
}

// ---------------------------------------------------------------------------
// Fallback: fp32 VALU GEMM (round-1, known-good)
// ---------------------------------------------------------------------------
__global__ __launch_bounds__(256) void enc_gemm_f32(
    const float* __restrict__ X, const float* __restrict__ W,
    const float* __restrict__ B1, const float* __restrict__ B2,
    float* __restrict__ PRE)
{
    __shared__ float Asm[16][128];
    __shared__ float Bsm[16][128];
    const int tid = threadIdx.x;
    const int m0 = blockIdx.y * 128;
    const int n0 = blockIdx.x * 128;
    const int tx = tid & 15;
    const int ty = tid >> 4;
    const int lr = tid >> 2;
    const int lk = (tid & 3) << 2;

    float acc[8][8];
    #pragma unroll
    for (int i = 0; i < 8; ++i)
        #pragma unroll
        for (int j = 0; j < 8; ++j) acc[i][j] = 0.f;

    const float* xp0 = X + (size_t)(m0 + lr) * D_MOD + lk;
    const float* xp1 = X + (size_t)(m0 + lr + 64) * D_MOD + lk;
    const float* wp0 = W + (size_t)(n0 + lr) * D_MOD + lk;
    const float* wp1 = W + (size_t)(n0 + lr + 64) * D_MOD + lk;

    for (int k0 = 0; k0 < D_MOD; k0 += 16) {
        const float4 a0 = *(const float4*)(xp0 + k0);
        const float4 a1 = *(const float4*)(xp1 + k0);
        const float4 b0 = *(const float4*)(wp0 + k0);
        const float4 b1 = *(const float4*)(wp1 + k0);
        __syncthreads();
        Asm[lk + 0][lr]      = a0.x; Asm[lk + 1][lr]      = a0.y;
        Asm[lk + 2][lr]      = a0.z; Asm[lk + 3][lr]      = a0.w;
        Asm[lk + 0][lr + 64] = a1.x; Asm[lk + 1][lr + 64] = a1.y;
        Asm[lk + 2][lr + 64] = a1.z; Asm[lk + 3][lr + 64] = a1.w;
        Bsm[lk + 0][lr]      = b0.x; Bsm[lk + 1][lr]      = b0.y;
        Bsm[lk + 2][lr]      = b0.z; Bsm[lk + 3][lr]      = b0.w;
        Bsm[lk + 0][lr + 64] = b1.x; Bsm[lk + 1][lr + 64] = b1.y;
        Bsm[lk + 2][lr + 64] = b1.z; Bsm[lk + 3][lr + 64] = b1.w;
        __syncthreads();
        #pragma unroll
        for (int kk = 0; kk < 16; ++kk) {
            float a[8], b[8];
            *(float4*)&a[0] = *(const float4*)&Asm[kk][ty * 8];
            *(float4*)&a[4] = *(const float4*)&Asm[kk][ty * 8 + 4];
            *(float4*)&b[0] = *(const float4*)&Bsm[kk][tx * 8];
            *(float4*)&b[4] = *(const float4*)&Bsm[kk][tx * 8 + 4];
            #pragma unroll
            for (int i = 0; i < 8; ++i)
                #pragma unroll
                for (int j = 0; j < 8; ++j)
                    acc[i][j] = fmaf(a[i], b[j], acc[i][j]);
        }
    }

    float bias[8];
    #pragma unroll
    for (int j = 0; j < 8; ++j) {
        const int col = n0 + tx * 8 + j;
        bias[j] = B1[col] + B2[col];
    }
    #pragma unroll
    for (int i = 0; i < 8; ++i) {
        const size_t off = (size_t)(m0 + ty * 8 + i) * D_LAT + n0 + tx * 8;
        float4 o0, o1;
        o0.x = acc[i][0] + bias[0]; o0.y = acc[i][1] + bias[1];
        o0.z = acc[i][2] + bias[2]; o0.w = acc[i][3] + bias[3];
        o1.x = acc[i][4] + bias[4]; o1.y = acc[i][5] + bias[5];
        o1.z = acc[i][6] + bias[6]; o1.w = acc[i][7] + bias[7];
        *(float4*)&PRE[off]     = o0;
        *(float4*)&PRE[off + 4] = o1;
    }
}

// ---------------------------------------------------------------------------
// Kernel: per-row top-16 via 2-round radix-select + short exact extraction.
// float4 I/O; decode gathers DT in f16; latents/recon stored nontemporal
// (streaming outputs, never re-read) via ext_vector types.
// ---------------------------------------------------------------------------
__global__ __launch_bounds__(256) void topk_decode(
    float* __restrict__ LAT, const f16_t* __restrict__ DT,
    const float* __restrict__ DW, float* __restrict__ REC, const int use_t)
{
    const int row = blockIdx.x;
    const int t = threadIdx.x;
    const int wv = t >> 6;
    const int ln = t & 63;
    float* prow = LAT + (size_t)row * D_LAT;
    f32x4* pv4 = (f32x4*)prow;

    __shared__ uint32_t hist[4096];     // 16KB, transposed layout
    __shared__ uint32_t h2[256];        // refinement histogram
    __shared__ uint32_t wsum[4];
    __shared__ uint32_t sh_b1, sh_cgt1, sh_prefix, sh_cgt2;
    __shared__ uint32_t s_wk[4];
    __shared__ int      s_wi[4];
    __shared__ float    topv[K_TOP];
    __shared__ int      topi[K_TOP];
    __shared__ uint32_t sh_cnt;

    // load row: 4 x 16B per thread (coalesced)
    float v[16];
    #pragma unroll
    for (int j = 0; j < 4; ++j) {
        const f32x4 f = pv4[t + 256 * j];
        v[j * 4 + 0] = f[0]; v[j * 4 + 1] = f[1];
        v[j * 4 + 2] = f[2]; v[j * 4 + 3] = f[3];
    }

    // monotone key: larger key <=> larger float (finite data)
    uint32_t key[16];
    #pragma unroll
    for (int jj = 0; jj < 16; ++jj) {
        const uint32_t b = __float_as_uint(v[jj]);
        key[jj] = (b & 0x80000000u) ? ~b : (b | 0x80000000u);
    }

    // phase 0: zero histograms (vector stores)
    u32x4* h4 = (u32x4*)hist;
    #pragma unroll
    for (int i = 0; i < 4; ++i) h4[t + 256 * i] = (u32x4)(0u);
    h2[t] = 0;
    if (t == 0) sh_cnt = 0;
    __syncthreads();

    // phase 1: 12-bit histogram (transposed addressing)
    #pragma unroll
    for (int jj = 0; jj < 16; ++jj) {
        const uint32_t bin = key[jj] >> 20;
        atomicAdd(&hist[(bin & 15u) * 256 + (bin >> 4)], 1u);
    }
    __syncthreads();

    // phase 2: block suffix-scan over 256 chunks of 16 bins; find rank-16 bin
    uint32_t s = 0;
    #pragma unroll
    for (int b = 0; b < 16; ++b) s += hist[b * 256 + t];
    uint32_t suf = s;                       // inclusive suffix within wave
    #pragma unroll
    for (int off = 1; off <= 32; off <<= 1) {
        const uint32_t o = __shfl_down(suf, off);
        if (ln + off < 64) suf += o;
    }
    if (ln == 0) wsum[wv] = suf;
    __syncthreads();
    uint32_t above = suf - s;               // lanes > ln, same wave
    for (int w2 = wv + 1; w2 < 4; ++w2) above += wsum[w2];
    if (above < K_TOP && above + s >= K_TOP) {   // unique owner chunk
        uint32_t acc = above;
        for (int b = 15; b >= 0; --b) {
            const uint32_t h = hist[b * 256 + t];
            if (acc + h >= K_TOP) { sh_b1 = (uint32_t)(t * 16 + b); sh_cgt1 = acc; break; }
            acc += h;
        }
    }
    __syncthreads();
    const uint32_t b1 = sh_b1;
    const uint32_t cgt1 = sh_cgt1;
    const uint32_t need1 = K_TOP - cgt1;

    // phase 3: refine on bits [19:12] among prefix-matched values
    #pragma unroll
    for (int jj = 0; jj < 16; ++jj)
        if ((key[jj] >> 20) == b1) atomicAdd(&h2[(key[jj] >> 12) & 255u], 1u);
    __syncthreads();

    // phase 4: wave 0 suffix-scans h2 (4 bins/lane)
    if (wv == 0) {
        const int base = ln * 4;
        const uint32_t s2 = h2[base] + h2[base + 1] + h2[base + 2] + h2[base + 3];
        uint32_t suf2 = s2;
        #pragma unroll
        for (int off = 1; off <= 32; off <<= 1) {
            const uint32_t o = __shfl_down(suf2, off);
            if (ln + off < 64) suf2 += o;
        }
        const uint32_t E = suf2 - s2;       // bins in lanes > ln
        if (E < need1 && E + s2 >= need1) {
            uint32_t acc = E;
            for (int b = 3; b >= 0; --b) {
                const uint32_t h = h2[base + b];
                if (acc + h >= need1) {
                    sh_prefix = (b1 << 8) | (uint32_t)(base + b);
                    sh_cgt2 = cgt1 + acc;
                    break;
                }
                acc += h;
            }
        }
    }
    __syncthreads();
    const uint32_t prefix = sh_prefix;
    const uint32_t need_in = K_TOP - sh_cgt2;   // >= 1, uniform

    // phase 5: selection by 20-bit prefix; exact extraction for the boundary
    // element index for slot jj: l = ((jj>>2)<<10) | (t<<2) | (jj&3)
    uint32_t sel = 0, candm = 0;
    #pragma unroll
    for (int jj = 0; jj < 16; ++jj) {
        const uint32_t p = key[jj] >> 12;
        if (p > prefix) sel |= 1u << jj;
        else if (p == prefix) candm |= 1u << jj;
    }
    for (uint32_t e = 0; e < need_in; ++e) {
        uint32_t bk = 0; int bi = 0x7FFFFFFF;
        #pragma unroll
        for (int jj = 0; jj < 16; ++jj) {
            if ((candm >> jj) & 1u) {
                const int lj = ((jj >> 2) << 10) | (t << 2) | (jj & 3);
                if (key[jj] > bk || (key[jj] == bk && lj < bi)) { bk = key[jj]; bi = lj; }
            }
        }
        #pragma unroll
        for (int off = 32; off >= 1; off >>= 1) {
            const uint32_t ok = __shfl_xor(bk, off);
            const int      oi = __shfl_xor(bi, off);
            if (ok > bk || (ok == bk && oi < bi)) { bk = ok; bi = oi; }
        }
        if (ln == 0) { s_wk[wv] = bk; s_wi[wv] = bi; }
        __syncthreads();
        uint32_t fk = s_wk[0]; int fi = s_wi[0];
        for (int w2 = 1; w2 < 4; ++w2)
            if (s_wk[w2] > fk || (s_wk[w2] == fk && s_wi[w2] < fi)) { fk = s_wk[w2]; fi = s_wi[w2]; }
        if (((fi >> 2) & 255) == t) {
            const int jj = (((fi >> 10) & 3) << 2) | (fi & 3);
            candm &= ~(1u << jj);
            sel   |=  (1u << jj);
        }
        __syncthreads();
    }

    // phase 6: sparse latents write (relu on selected), nontemporal 16B
    #pragma unroll
    for (int j = 0; j < 4; ++j) {
        f32x4 o;
        o[0] = ((sel >> (j * 4 + 0)) & 1u) ? fmaxf(v[j * 4 + 0], 0.f) : 0.f;
        o[1] = ((sel >> (j * 4 + 1)) & 1u) ? fmaxf(v[j * 4 + 1], 0.f) : 0.f;
        o[2] = ((sel >> (j * 4 + 2)) & 1u) ? fmaxf(v[j * 4 + 2], 0.f) : 0.f;
        o[3] = ((sel >> (j * 4 + 3)) & 1u) ? fmaxf(v[j * 4 + 3], 0.f) : 0.f;
        __builtin_nontemporal_store(o, &pv4[t + 256 * j]);
    }

    // phase 7: compact selected (val, idx) -> LDS (exactly 16)
    #pragma unroll
    for (int jj = 0; jj < 16; ++jj) {
        if ((sel >> jj) & 1u) {
            const uint32_t slot = atomicAdd(&sh_cnt, 1u);
            topv[slot] = v[jj];
            topi[slot] = ((jj >> 2) << 10) | (t << 2) | (jj & 3);
        }
    }
    __syncthreads();

    // phase 8: decode recon[row, d] = sum_k relu(val_k) * dec_w[d, l_k]
    f32x4 racc = (f32x4)(0.0f);
    if (use_t) {
        #pragma unroll
        for (int k = 0; k < K_TOP; ++k) {
            const float val = fmaxf(topv[k], 0.f);
            const half4 wr = *(const half4*)(DT + (size_t)topi[k] * D_MOD + 4 * t);
            racc[0] = fmaf(val, (float)wr[0], racc[0]);
            racc[1] = fmaf(val, (float)wr[1], racc[1]);
            racc[2] = fmaf(val, (float)wr[2], racc[2]);
            racc[3] = fmaf(val, (float)wr[3], racc[3]);
        }
    } else {
        #pragma unroll
        for (int k = 0; k < K_TOP; ++k) {
            const float val = fmaxf(topv[k], 0.f);
            const int   li  = topi[k];
            racc[0] = fmaf(val, DW[(size_t)(4 * t + 0) * D_LAT + li], racc[0]);
            racc[1] = fmaf(val, DW[(size_t)(4 * t + 1) * D_LAT + li], racc[1]);
            racc[2] = fmaf(val, DW[(size_t)(4 * t + 2) * D_LAT + li], racc[2]);
            racc[3] = fmaf(val, DW[(size_t)(4 * t + 3) * D_LAT + li], racc[3]);
        }
    }
    __builtin_nontemporal_store(racc, &((f32x4*)(REC + (size_t)row * D_MOD))[t]);
}

// ---------------------------------------------------------------------------
extern "C" void kernel_launch(void* const* d_in, const int* in_sizes, int n_in,
                              void* d_out, int out_size, void* d_ws, size_t ws_size,
                              hipStream_t stream)
{
    const float* x      = (const float*)d_in[0];
    const float* enc_w  = (const float*)d_in[1];
    const float* enc_b  = (const float*)d_in[2];
    const float* enc_b2 = (const float*)d_in[3];
    const float* dec_w  = (const float*)d_in[4];

    float* recon   = (float*)d_out;                    // [16384,1024]
    float* latents = recon + (size_t)N_ROWS * D_MOD;   // [16384,4096]

    char* ws = (char*)d_ws;
    // ws layout (bytes): decT f16 [0,8.4M) | pad | xh | xl | wh | wl (f16)
    f16_t* decT = (f16_t*)ws;
    f16_t* xh = (f16_t*)(ws + 16777216);
    f16_t* xl = (f16_t*)(ws + 50331648);   // = xh + XL_OFF elems
    f16_t* wh = (f16_t*)(ws + 83886080);
    f16_t* wl = (f16_t*)(ws + 92274688);   // = wh + WL_OFF elems
    const size_t need_fast = 100663296;
    const int fast = (ws_size >= need_fast) ? 1 : 0;

    if (fast) {
        prep<<<PREP_XBLK + PREP_WBLK + PREP_TBLK, 256, 0, stream>>>(
            x, enc_w, dec_w, xh, xl, wh, wl, decT);
        enc_gemm_f16<<<(N_ROWS / 128) * (D_LAT / 128), 256, 0, stream>>>(
            xh, wh, enc_b, enc_b2, latents);
        topk_decode<<<N_ROWS, 256, 0, stream>>>(latents, decT, dec_w, recon, 1);
    } else {
        enc_gemm_f32<<<dim3(D_LAT / 128, N_ROWS / 128), 256, 0, stream>>>(
            x, enc_w, enc_b, enc_b2, latents);
        topk_decode<<<N_ROWS, 256, 0, stream>>>(latents, (const f16_t*)ws, dec_w, recon, 0);
    }
}

// Round 16
// 586.429 us; speedup vs baseline: 1.0677x; 1.0492x over previous
//
#include <hip/hip_runtime.h>
#include <cstdint>
#include <cstddef>

// Problem constants
#define N_ROWS  16384      // 4*4096 tokens
#define D_MOD   1024
#define D_LAT   4096
#define K_TOP   16

typedef _Float16 f16_t;
typedef _Float16 half8 __attribute__((ext_vector_type(8)));
typedef _Float16 half4 __attribute__((ext_vector_type(4)));
typedef float f32x4 __attribute__((ext_vector_type(4)));
typedef unsigned short u16x4 __attribute__((ext_vector_type(4)));
typedef unsigned int u32x4 __attribute__((ext_vector_type(4)));

// ws layout element offsets (f16) — must match kernel_launch
#define XL_OFF  16777216u   // (50331648-16777216)/2
#define WL_OFF  4194304u    // (92274688-83886080)/2

// prep-kernel grid segmentation
#define PREP_XBLK 16384     // x split: 16384*1024/4/256
#define PREP_WBLK 4096      // w split: 4096*1024/4/256
#define PREP_TBLK 4096      // transpose: 128*32

// ---------------------------------------------------------------------------
// global_load_lds helper (16B per lane, LDS dest = wave-uniform base + lane*16)
// ---------------------------------------------------------------------------
__device__ __forceinline__ void gload_lds16(const void* g, void* l) {
    __builtin_amdgcn_global_load_lds(
        (const __attribute__((address_space(1))) void*)g,
        (__attribute__((address_space(3))) void*)l, 16, 0, 0);
}

// ---------------------------------------------------------------------------
// Fused prep kernel: {split x, split enc_w, transpose dec_w} in ONE launch
// (all independent; branch on blockIdx). Split outputs stored nontemporal
// (streaming, read once by GEMM much later; 118MB >> L2 anyway).
// ---------------------------------------------------------------------------
__global__ __launch_bounds__(256) void prep(
    const float* __restrict__ x, const float* __restrict__ enc_w,
    const float* __restrict__ dec_w,
    f16_t* __restrict__ xh, f16_t* __restrict__ xl,
    f16_t* __restrict__ wh, f16_t* __restrict__ wl,
    f16_t* __restrict__ DT)
{
    __shared__ float tile[32][33];
    const int bid = blockIdx.x;

    if (bid < PREP_XBLK + PREP_WBLK) {
        // ---- split fp32 -> f16 hi + f16 lo*2^11 (exact Fast2Sum residual) --
        const float* src; f16_t* hi; f16_t* lo; int i;
        if (bid < PREP_XBLK) {
            src = x;     hi = xh; lo = xl;
            i = bid * 256 + threadIdx.x;
        } else {
            src = enc_w; hi = wh; lo = wl;
            i = (bid - PREP_XBLK) * 256 + threadIdx.x;
        }
        const f32x4 v = ((const f32x4*)src)[i];
        union { f16_t h[4]; u16x4 u; } ph, pl;
        ph.h[0] = (f16_t)v[0]; ph.h[1] = (f16_t)v[1];
        ph.h[2] = (f16_t)v[2]; ph.h[3] = (f16_t)v[3];
        pl.h[0] = (f16_t)((v[0] - (float)ph.h[0]) * 2048.0f);
        pl.h[1] = (f16_t)((v[1] - (float)ph.h[1]) * 2048.0f);
        pl.h[2] = (f16_t)((v[2] - (float)ph.h[2]) * 2048.0f);
        pl.h[3] = (f16_t)((v[3] - (float)ph.h[3]) * 2048.0f);
        __builtin_nontemporal_store(ph.u, &((u16x4*)hi)[i]);
        __builtin_nontemporal_store(pl.u, &((u16x4*)lo)[i]);
    } else {
        // ---- transpose dec_w [1024][4096] -> decT f16 [4096][1024] ---------
        const int tb = bid - PREP_XBLK - PREP_WBLK;
        const int l0 = (tb & 127) * 32;   // along D_LAT
        const int d0 = (tb >> 7) * 32;    // along D_MOD
        const int tx = threadIdx.x & 31;
        const int ty = threadIdx.x >> 5;
        #pragma unroll
        for (int i = 0; i < 32; i += 8)
            tile[ty + i][tx] = dec_w[(size_t)(d0 + ty + i) * D_LAT + l0 + tx];
        __syncthreads();
        #pragma unroll
        for (int i = 0; i < 32; i += 8)
            DT[(size_t)(l0 + ty + i) * D_MOD + d0 + tx] = (f16_t)tile[tx][ty + i];
    }
}

// ---------------------------------------------------------------------------
// Fused MFMA GEMM, BK=64, 4 waves, wave tile 64x64 (round-12 version —
// measured best of 8 structure variants r6-r13: 424us, MfmaUtil 44%).
// pre = xh*wh + (xh*wl + xl*wh)/2048 + bias.
// A-subtile source pipeline; 64KB LDS 1-buffer 2-barrier loop;
// swizzle (chunk ^= row&7) via pre-swizzled global source, linear dest.
// r15 lesson: nontemporal pre store REGRESSED (-36us: bypasses L2 write-
// combining, FETCH unchanged) -> regular stores restored (r12 verbatim).
// ---------------------------------------------------------------------------
__global__ __launch_bounds__(256, 2) void enc_gemm_f16(
    const f16_t* __restrict__ XH, const f16_t* __restrict__ WH,
    const float* __restrict__ B1, const float* __restrict__ B2,
    float* __restrict__ PRE)
{
    __shared__ char smem[65536];
    char* AsH = smem;
    char* AsL = smem + 16384;
    char* BsH = smem + 32768;
    char* BsL = smem + 49152;

    const int tid = threadIdx.x;
    const int w = tid >> 6;          // 0..3
    const int l = tid & 63;

    // XCD-bijective swizzle (4096 blocks % 8 == 0)
    const int bid = blockIdx.x;
    const int swz = (bid & 7) * 512 + (bid >> 3);
    const int bx = swz & 31;          // 32 n-blocks
    const int by = swz >> 5;          // 128 m-blocks
    const int m0 = by * 128, n0 = bx * 128;
    const int wm = w >> 1, wn = w & 1;

    f32x4 acc1[4][4], acc2[4][4];
    #pragma unroll
    for (int i = 0; i < 4; ++i)
        #pragma unroll
        for (int j = 0; j < 4; ++j) {
            acc1[i][j] = (f32x4)(0.0f);
            acc2[i][j] = (f32x4)(0.0f);
        }

    const int srow  = l >> 3;                 // 0..7 within 8-row chunk
    const int sclog = (l & 7) ^ srow;         // pre-swizzled logical chunk
    const size_t abase = (size_t)m0 * D_MOD;
    const size_t bbase = (size_t)n0 * D_MOD;
    const f16_t* XL = XH + XL_OFF;            // constant ws offsets
    const f16_t* WL = WH + WL_OFF;

    for (int k0 = 0; k0 < D_MOD; k0 += 64) {
        __syncthreads();   // all waves done reading LDS from previous step
        #pragma unroll
        for (int i = 0; i < 4; ++i) {
            const int cidx = i * 4 + w;                // 8-row chunk 0..15
            const size_t goff = (size_t)(cidx * 8 + srow) * D_MOD + k0 + sclog * 8;
            const int ldst = cidx * 1024;
            gload_lds16(XH + abase + goff, AsH + ldst);
            gload_lds16(XL + abase + goff, AsL + ldst);
            gload_lds16(WH + bbase + goff, BsH + ldst);
            gload_lds16(WL + bbase + goff, BsL + ldst);
        }
        __syncthreads();   // vmcnt(0) drained by compiler before barrier

        #pragma unroll
        for (int kk = 0; kk < 2; ++kk) {
            const int c = ((kk * 4) + (l >> 4)) ^ (l & 7);  // swizzled chunk
            half8 bh[4], bl[4];
            #pragma unroll
            for (int ni = 0; ni < 4; ++ni) {
                const int col = wn * 64 + ni * 16 + (l & 15);
                bh[ni] = *(const half8*)(BsH + col * 128 + c * 16);
                bl[ni] = *(const half8*)(BsL + col * 128 + c * 16);
            }
            const int rbase = wm * 64 + (l & 15);
            half8 ah = *(const half8*)(AsH + rbase * 128 + c * 16);
            half8 al = *(const half8*)(AsL + rbase * 128 + c * 16);
            #pragma unroll
            for (int mi = 0; mi < 4; ++mi) {
                half8 ah_n = ah, al_n = al;
                if (mi < 3) {   // issue NEXT subtile's reads before MFMAs
                    const int row = rbase + (mi + 1) * 16;
                    ah_n = *(const half8*)(AsH + row * 128 + c * 16);
                    al_n = *(const half8*)(AsL + row * 128 + c * 16);
                }
                #pragma unroll
                for (int ni = 0; ni < 4; ++ni)
                    acc1[mi][ni] = __builtin_amdgcn_mfma_f32_16x16x32_f16(
                        ah, bh[ni], acc1[mi][ni], 0, 0, 0);
                #pragma unroll
                for (int ni = 0; ni < 4; ++ni)
                    acc2[mi][ni] = __builtin_amdgcn_mfma_f32_16x16x32_f16(
                        ah, bl[ni], acc2[mi][ni], 0, 0, 0);
                #pragma unroll
                for (int ni = 0; ni < 4; ++ni)
                    acc2[mi][ni] = __builtin_amdgcn_mfma_f32_16x16x32_f16(
                        al, bh[ni], acc2[mi][ni], 0, 0, 0);
                ah = ah_n; al = al_n;
            }
        }
    }

    // epilogue: pre = acc1 + acc2/2048 + bias  (regular stores — r12)
    const int lrow = (l >> 4) * 4;
    const int lcol = l & 15;
    #pragma unroll
    for (int ni = 0; ni < 4; ++ni) {
        const int col = n0 + wn * 64 + ni * 16 + lcol;
        const float bias = B1[col] + B2[col];
        #pragma unroll
        for (int mi = 0; mi < 4; ++mi) {
            const int row = m0 + wm * 64 + mi * 16 + lrow;
            #pragma unroll
            for (int j = 0; j < 4; ++j)
                PRE[(size_t)(row + j) * D_LAT + col] =
                    acc1[mi][ni][j] + acc2[mi][ni][j] * (1.0f / 2048.0f) + bias;
        }
    }
}

// ---------------------------------------------------------------------------
// Fallback: fp32 VALU GEMM (round-1, known-good)
// ---------------------------------------------------------------------------
__global__ __launch_bounds__(256) void enc_gemm_f32(
    const float* __restrict__ X, const float* __restrict__ W,
    const float* __restrict__ B1, const float* __restrict__ B2,
    float* __restrict__ PRE)
{
    __shared__ float Asm[16][128];
    __shared__ float Bsm[16][128];
    const int tid = threadIdx.x;
    const int m0 = blockIdx.y * 128;
    const int n0 = blockIdx.x * 128;
    const int tx = tid & 15;
    const int ty = tid >> 4;
    const int lr = tid >> 2;
    const int lk = (tid & 3) << 2;

    float acc[8][8];
    #pragma unroll
    for (int i = 0; i < 8; ++i)
        #pragma unroll
        for (int j = 0; j < 8; ++j) acc[i][j] = 0.f;

    const float* xp0 = X + (size_t)(m0 + lr) * D_MOD + lk;
    const float* xp1 = X + (size_t)(m0 + lr + 64) * D_MOD + lk;
    const float* wp0 = W + (size_t)(n0 + lr) * D_MOD + lk;
    const float* wp1 = W + (size_t)(n0 + lr + 64) * D_MOD + lk;

    for (int k0 = 0; k0 < D_MOD; k0 += 16) {
        const float4 a0 = *(const float4*)(xp0 + k0);
        const float4 a1 = *(const float4*)(xp1 + k0);
        const float4 b0 = *(const float4*)(wp0 + k0);
        const float4 b1 = *(const float4*)(wp1 + k0);
        __syncthreads();
        Asm[lk + 0][lr]      = a0.x; Asm[lk + 1][lr]      = a0.y;
        Asm[lk + 2][lr]      = a0.z; Asm[lk + 3][lr]      = a0.w;
        Asm[lk + 0][lr + 64] = a1.x; Asm[lk + 1][lr + 64] = a1.y;
        Asm[lk + 2][lr + 64] = a1.z; Asm[lk + 3][lr + 64] = a1.w;
        Bsm[lk + 0][lr]      = b0.x; Bsm[lk + 1][lr]      = b0.y;
        Bsm[lk + 2][lr]      = b0.z; Bsm[lk + 3][lr]      = b0.w;
        Bsm[lk + 0][lr + 64] = b1.x; Bsm[lk + 1][lr + 64] = b1.y;
        Bsm[lk + 2][lr + 64] = b1.z; Bsm[lk + 3][lr + 64] = b1.w;
        __syncthreads();
        #pragma unroll
        for (int kk = 0; kk < 16; ++kk) {
            float a[8], b[8];
            *(float4*)&a[0] = *(const float4*)&Asm[kk][ty * 8];
            *(float4*)&a[4] = *(const float4*)&Asm[kk][ty * 8 + 4];
            *(float4*)&b[0] = *(const float4*)&Bsm[kk][tx * 8];
            *(float4*)&b[4] = *(const float4*)&Bsm[kk][tx * 8 + 4];
            #pragma unroll
            for (int i = 0; i < 8; ++i)
                #pragma unroll
                for (int j = 0; j < 8; ++j)
                    acc[i][j] = fmaf(a[i], b[j], acc[i][j]);
        }
    }

    float bias[8];
    #pragma unroll
    for (int j = 0; j < 8; ++j) {
        const int col = n0 + tx * 8 + j;
        bias[j] = B1[col] + B2[col];
    }
    #pragma unroll
    for (int i = 0; i < 8; ++i) {
        const size_t off = (size_t)(m0 + ty * 8 + i) * D_LAT + n0 + tx * 8;
        float4 o0, o1;
        o0.x = acc[i][0] + bias[0]; o0.y = acc[i][1] + bias[1];
        o0.z = acc[i][2] + bias[2]; o0.w = acc[i][3] + bias[3];
        o1.x = acc[i][4] + bias[4]; o1.y = acc[i][5] + bias[5];
        o1.z = acc[i][6] + bias[6]; o1.w = acc[i][7] + bias[7];
        *(float4*)&PRE[off]     = o0;
        *(float4*)&PRE[off + 4] = o1;
    }
}

// ---------------------------------------------------------------------------
// Kernel: per-row top-16 via 2-round radix-select + short exact extraction.
// float4 I/O; decode gathers DT in f16; latents/recon stored nontemporal
// (streaming outputs, never re-read) via ext_vector types. (r15, measured)
// ---------------------------------------------------------------------------
__global__ __launch_bounds__(256) void topk_decode(
    float* __restrict__ LAT, const f16_t* __restrict__ DT,
    const float* __restrict__ DW, float* __restrict__ REC, const int use_t)
{
    const int row = blockIdx.x;
    const int t = threadIdx.x;
    const int wv = t >> 6;
    const int ln = t & 63;
    float* prow = LAT + (size_t)row * D_LAT;
    f32x4* pv4 = (f32x4*)prow;

    __shared__ uint32_t hist[4096];     // 16KB, transposed layout
    __shared__ uint32_t h2[256];        // refinement histogram
    __shared__ uint32_t wsum[4];
    __shared__ uint32_t sh_b1, sh_cgt1, sh_prefix, sh_cgt2;
    __shared__ uint32_t s_wk[4];
    __shared__ int      s_wi[4];
    __shared__ float    topv[K_TOP];
    __shared__ int      topi[K_TOP];
    __shared__ uint32_t sh_cnt;

    // load row: 4 x 16B per thread (coalesced)
    float v[16];
    #pragma unroll
    for (int j = 0; j < 4; ++j) {
        const f32x4 f = pv4[t + 256 * j];
        v[j * 4 + 0] = f[0]; v[j * 4 + 1] = f[1];
        v[j * 4 + 2] = f[2]; v[j * 4 + 3] = f[3];
    }

    // monotone key: larger key <=> larger float (finite data)
    uint32_t key[16];
    #pragma unroll
    for (int jj = 0; jj < 16; ++jj) {
        const uint32_t b = __float_as_uint(v[jj]);
        key[jj] = (b & 0x80000000u) ? ~b : (b | 0x80000000u);
    }

    // phase 0: zero histograms (vector stores)
    u32x4* h4 = (u32x4*)hist;
    #pragma unroll
    for (int i = 0; i < 4; ++i) h4[t + 256 * i] = (u32x4)(0u);
    h2[t] = 0;
    if (t == 0) sh_cnt = 0;
    __syncthreads();

    // phase 1: 12-bit histogram (transposed addressing)
    #pragma unroll
    for (int jj = 0; jj < 16; ++jj) {
        const uint32_t bin = key[jj] >> 20;
        atomicAdd(&hist[(bin & 15u) * 256 + (bin >> 4)], 1u);
    }
    __syncthreads();

    // phase 2: block suffix-scan over 256 chunks of 16 bins; find rank-16 bin
    uint32_t s = 0;
    #pragma unroll
    for (int b = 0; b < 16; ++b) s += hist[b * 256 + t];
    uint32_t suf = s;                       // inclusive suffix within wave
    #pragma unroll
    for (int off = 1; off <= 32; off <<= 1) {
        const uint32_t o = __shfl_down(suf, off);
        if (ln + off < 64) suf += o;
    }
    if (ln == 0) wsum[wv] = suf;
    __syncthreads();
    uint32_t above = suf - s;               // lanes > ln, same wave
    for (int w2 = wv + 1; w2 < 4; ++w2) above += wsum[w2];
    if (above < K_TOP && above + s >= K_TOP) {   // unique owner chunk
        uint32_t acc = above;
        for (int b = 15; b >= 0; --b) {
            const uint32_t h = hist[b * 256 + t];
            if (acc + h >= K_TOP) { sh_b1 = (uint32_t)(t * 16 + b); sh_cgt1 = acc; break; }
            acc += h;
        }
    }
    __syncthreads();
    const uint32_t b1 = sh_b1;
    const uint32_t cgt1 = sh_cgt1;
    const uint32_t need1 = K_TOP - cgt1;

    // phase 3: refine on bits [19:12] among prefix-matched values
    #pragma unroll
    for (int jj = 0; jj < 16; ++jj)
        if ((key[jj] >> 20) == b1) atomicAdd(&h2[(key[jj] >> 12) & 255u], 1u);
    __syncthreads();

    // phase 4: wave 0 suffix-scans h2 (4 bins/lane)
    if (wv == 0) {
        const int base = ln * 4;
        const uint32_t s2 = h2[base] + h2[base + 1] + h2[base + 2] + h2[base + 3];
        uint32_t suf2 = s2;
        #pragma unroll
        for (int off = 1; off <= 32; off <<= 1) {
            const uint32_t o = __shfl_down(suf2, off);
            if (ln + off < 64) suf2 += o;
        }
        const uint32_t E = suf2 - s2;       // bins in lanes > ln
        if (E < need1 && E + s2 >= need1) {
            uint32_t acc = E;
            for (int b = 3; b >= 0; --b) {
                const uint32_t h = h2[base + b];
                if (acc + h >= need1) {
                    sh_prefix = (b1 << 8) | (uint32_t)(base + b);
                    sh_cgt2 = cgt1 + acc;
                    break;
                }
                acc += h;
            }
        }
    }
    __syncthreads();
    const uint32_t prefix = sh_prefix;
    const uint32_t need_in = K_TOP - sh_cgt2;   // >= 1, uniform

    // phase 5: selection by 20-bit prefix; exact extraction for the boundary
    // element index for slot jj: l = ((jj>>2)<<10) | (t<<2) | (jj&3)
    uint32_t sel = 0, candm = 0;
    #pragma unroll
    for (int jj = 0; jj < 16; ++jj) {
        const uint32_t p = key[jj] >> 12;
        if (p > prefix) sel |= 1u << jj;
        else if (p == prefix) candm |= 1u << jj;
    }
    for (uint32_t e = 0; e < need_in; ++e) {
        uint32_t bk = 0; int bi = 0x7FFFFFFF;
        #pragma unroll
        for (int jj = 0; jj < 16; ++jj) {
            if ((candm >> jj) & 1u) {
                const int lj = ((jj >> 2) << 10) | (t << 2) | (jj & 3);
                if (key[jj] > bk || (key[jj] == bk && lj < bi)) { bk = key[jj]; bi = lj; }
            }
        }
        #pragma unroll
        for (int off = 32; off >= 1; off >>= 1) {
            const uint32_t ok = __shfl_xor(bk, off);
            const int      oi = __shfl_xor(bi, off);
            if (ok > bk || (ok == bk && oi < bi)) { bk = ok; bi = oi; }
        }
        if (ln == 0) { s_wk[wv] = bk; s_wi[wv] = bi; }
        __syncthreads();
        uint32_t fk = s_wk[0]; int fi = s_wi[0];
        for (int w2 = 1; w2 < 4; ++w2)
            if (s_wk[w2] > fk || (s_wk[w2] == fk && s_wi[w2] < fi)) { fk = s_wk[w2]; fi = s_wi[w2]; }
        if (((fi >> 2) & 255) == t) {
            const int jj = (((fi >> 10) & 3) << 2) | (fi & 3);
            candm &= ~(1u << jj);
            sel   |=  (1u << jj);
        }
        __syncthreads();
    }

    // phase 6: sparse latents write (relu on selected), nontemporal 16B
    #pragma unroll
    for (int j = 0; j < 4; ++j) {
        f32x4 o;
        o[0] = ((sel >> (j * 4 + 0)) & 1u) ? fmaxf(v[j * 4 + 0], 0.f) : 0.f;
        o[1] = ((sel >> (j * 4 + 1)) & 1u) ? fmaxf(v[j * 4 + 1], 0.f) : 0.f;
        o[2] = ((sel >> (j * 4 + 2)) & 1u) ? fmaxf(v[j * 4 + 2], 0.f) : 0.f;
        o[3] = ((sel >> (j * 4 + 3)) & 1u) ? fmaxf(v[j * 4 + 3], 0.f) : 0.f;
        __builtin_nontemporal_store(o, &pv4[t + 256 * j]);
    }

    // phase 7: compact selected (val, idx) -> LDS (exactly 16)
    #pragma unroll
    for (int jj = 0; jj < 16; ++jj) {
        if ((sel >> jj) & 1u) {
            const uint32_t slot = atomicAdd(&sh_cnt, 1u);
            topv[slot] = v[jj];
            topi[slot] = ((jj >> 2) << 10) | (t << 2) | (jj & 3);
        }
    }
    __syncthreads();

    // phase 8: decode recon[row, d] = sum_k relu(val_k) * dec_w[d, l_k]
    f32x4 racc = (f32x4)(0.0f);
    if (use_t) {
        #pragma unroll
        for (int k = 0; k < K_TOP; ++k) {
            const float val = fmaxf(topv[k], 0.f);
            const half4 wr = *(const half4*)(DT + (size_t)topi[k] * D_MOD + 4 * t);
            racc[0] = fmaf(val, (float)wr[0], racc[0]);
            racc[1] = fmaf(val, (float)wr[1], racc[1]);
            racc[2] = fmaf(val, (float)wr[2], racc[2]);
            racc[3] = fmaf(val, (float)wr[3], racc[3]);
        }
    } else {
        #pragma unroll
        for (int k = 0; k < K_TOP; ++k) {
            const float val = fmaxf(topv[k], 0.f);
            const int   li  = topi[k];
            racc[0] = fmaf(val, DW[(size_t)(4 * t + 0) * D_LAT + li], racc[0]);
            racc[1] = fmaf(val, DW[(size_t)(4 * t + 1) * D_LAT + li], racc[1]);
            racc[2] = fmaf(val, DW[(size_t)(4 * t + 2) * D_LAT + li], racc[2]);
            racc[3] = fmaf(val, DW[(size_t)(4 * t + 3) * D_LAT + li], racc[3]);
        }
    }
    __builtin_nontemporal_store(racc, &((f32x4*)(REC + (size_t)row * D_MOD))[t]);
}

// ---------------------------------------------------------------------------
extern "C" void kernel_launch(void* const* d_in, const int* in_sizes, int n_in,
                              void* d_out, int out_size, void* d_ws, size_t ws_size,
                              hipStream_t stream)
{
    const float* x      = (const float*)d_in[0];
    const float* enc_w  = (const float*)d_in[1];
    const float* enc_b  = (const float*)d_in[2];
    const float* enc_b2 = (const float*)d_in[3];
    const float* dec_w  = (const float*)d_in[4];

    float* recon   = (float*)d_out;                    // [16384,1024]
    float* latents = recon + (size_t)N_ROWS * D_MOD;   // [16384,4096]

    char* ws = (char*)d_ws;
    // ws layout (bytes): decT f16 [0,8.4M) | pad | xh | xl | wh | wl (f16)
    f16_t* decT = (f16_t*)ws;
    f16_t* xh = (f16_t*)(ws + 16777216);
    f16_t* xl = (f16_t*)(ws + 50331648);   // = xh + XL_OFF elems
    f16_t* wh = (f16_t*)(ws + 83886080);
    f16_t* wl = (f16_t*)(ws + 92274688);   // = wh + WL_OFF elems
    const size_t need_fast = 100663296;
    const int fast = (ws_size >= need_fast) ? 1 : 0;

    if (fast) {
        prep<<<PREP_XBLK + PREP_WBLK + PREP_TBLK, 256, 0, stream>>>(
            x, enc_w, dec_w, xh, xl, wh, wl, decT);
        enc_gemm_f16<<<(N_ROWS / 128) * (D_LAT / 128), 256, 0, stream>>>(
            xh, wh, enc_b, enc_b2, latents);
        topk_decode<<<N_ROWS, 256, 0, stream>>>(latents, decT, dec_w, recon, 1);
    } else {
        enc_gemm_f32<<<dim3(D_LAT / 128, N_ROWS / 128), 256, 0, stream>>>(
            x, enc_w, enc_b, enc_b2, latents);
        topk_decode<<<N_ROWS, 256, 0, stream>>>(latents, (const f16_t*)ws, dec_w, recon, 0);
    }
}